// Round 1
// baseline (3150.291 us; speedup 1.0000x reference)
//
#include <hip/hip_runtime.h>
#include <cstdint>

#define DEV static __device__ __forceinline__

typedef unsigned short u16;
typedef unsigned int   u32;
typedef __attribute__((ext_vector_type(8))) short bf16x8;
typedef __attribute__((ext_vector_type(4))) float f32x4;

constexpr int TT   = 8192;   // tokens = 4*2048
constexpr int DM   = 1024;
constexpr int DHID = 4096;
constexpr int MPAD = 17408;  // 136 * 128 (worst-case padded routed rows)

// ---- ws layout (bytes) ----
constexpr size_t OFF_R0 = 0;            // 142,606,336: h bf16 [MPAD][4096]; earlier hosts qkv_f32 (100.7MB) then attn_out f32 (33.6MB)
constexpr size_t OFF_R1 = 142606336;    //  35,651,584: ctx f32 [T][1024] then y bf16 [MPAD][1024]
constexpr size_t OFF_R2 = 178257920;    //  33,554,432: x f32 (LN1 out)
constexpr size_t OFF_R3 = 211812352;    //  35,651,584: xg bf16 [MPAD][1024]
constexpr size_t OFF_RT = 247463936;    //  routing scratch

DEV u16 f2b(float f){ u32 b = __builtin_bit_cast(u32, f); return (u16)((b + 0x7FFFu + ((b>>16)&1u))>>16); }
DEV float b2f(u16 u){ u32 b = ((u32)u)<<16; return __builtin_bit_cast(float, b); }

// ---------------------------------------------------------------------------
// fp32 tiled GEMM: C[M,N] = A[M,K] @ W[N,K]^T + bias (+resid). 64x64 tile, BK=16.
// ---------------------------------------------------------------------------
template<int RESID>
__global__ __launch_bounds__(256) void gemm_f32_kernel(
    const float* __restrict__ A, const float* __restrict__ W,
    const float* __restrict__ bias, const float* __restrict__ resid,
    float* __restrict__ C, int K, int N)
{
  __shared__ float As[16][72];
  __shared__ float Bs[16][72];
  const int m0 = blockIdx.y*64, n0 = blockIdx.x*64;
  const int t  = threadIdx.x;
  const int qi = t>>4, kj = t&15;      // 16x16 thread grid, 4x4 micro-tile
  const int sr = t>>2, sc = (t&3)*4;   // staging: one float4 per matrix
  float acc[4][4] = {};
  const float* Ap = A + (size_t)(m0+sr)*K + sc;
  const float* Wp = W + (size_t)(n0+sr)*K + sc;
  for (int k0 = 0; k0 < K; k0 += 16){
    __syncthreads();
    float4 a = *(const float4*)(Ap + k0);
    float4 b = *(const float4*)(Wp + k0);
    As[sc+0][sr]=a.x; As[sc+1][sr]=a.y; As[sc+2][sr]=a.z; As[sc+3][sr]=a.w;
    Bs[sc+0][sr]=b.x; Bs[sc+1][sr]=b.y; Bs[sc+2][sr]=b.z; Bs[sc+3][sr]=b.w;
    __syncthreads();
    #pragma unroll
    for (int k=0;k<16;k++){
      const float4 a4 = *(const float4*)&As[k][qi*4];
      const float4 b4 = *(const float4*)&Bs[k][kj*4];
      float av[4]={a4.x,a4.y,a4.z,a4.w}, bv[4]={b4.x,b4.y,b4.z,b4.w};
      #pragma unroll
      for (int i=0;i<4;i++)
        #pragma unroll
        for (int j=0;j<4;j++) acc[i][j] = fmaf(av[i], bv[j], acc[i][j]);
    }
  }
  const float4 b4 = *(const float4*)&bias[n0 + kj*4];
  const float bb[4] = {b4.x,b4.y,b4.z,b4.w};
  #pragma unroll
  for (int i=0;i<4;i++){
    const int gm = m0 + qi*4 + i;
    float r[4];
    #pragma unroll
    for (int j=0;j<4;j++) r[j] = acc[i][j] + bb[j];
    if (RESID){
      const float4 rv = *(const float4*)&resid[(size_t)gm*N + n0 + kj*4];
      r[0]+=rv.x; r[1]+=rv.y; r[2]+=rv.z; r[3]+=rv.w;
    }
    *(float4*)&C[(size_t)gm*N + n0 + kj*4] = make_float4(r[0],r[1],r[2],r[3]);
  }
}

// ---------------------------------------------------------------------------
// fp32 flash attention. grid: (32 qtiles, 64 b*h). 64 q-rows/block, 64-key tiles.
// Qs/Ks stored [d][key] with 16B-chunk XOR swizzle; Vs/Ps row-major.
// ---------------------------------------------------------------------------
__global__ __launch_bounds__(256) void attn_kernel(const float* __restrict__ qkv,
                                                   float* __restrict__ ctx)
{
  __shared__ float Qs[64*72];
  __shared__ float Ks[64*72];
  __shared__ float Vs[64*72];
  __shared__ float Ps[64*72];
  const int bh = blockIdx.y, bb = bh>>4, h = bh&15;
  const int tb = bb*2048, q0 = blockIdx.x*64;
  const int t  = threadIdx.x;
  const int qi = t>>4, kj = t&15;
  const int go = h*64;
  const int sg = (t>>4)*4;   // 4-row group for transposed staging
  const int sl = t&15;
  // stage Q (scaled by 1/8 — exact)
  #pragma unroll
  for (int it=0; it<4; it++){
    const int d = sl + 16*it;
    float v0 = qkv[(size_t)(tb+q0+sg+0)*3072 + go + d];
    float v1 = qkv[(size_t)(tb+q0+sg+1)*3072 + go + d];
    float v2 = qkv[(size_t)(tb+q0+sg+2)*3072 + go + d];
    float v3 = qkv[(size_t)(tb+q0+sg+3)*3072 + go + d];
    *(float4*)&Qs[d*72 + (((sg>>2) ^ (d&15))<<2)] =
        make_float4(v0*0.125f, v1*0.125f, v2*0.125f, v3*0.125f);
  }
  float m_[4] = {-1e30f,-1e30f,-1e30f,-1e30f};
  float l_[4] = {0.f,0.f,0.f,0.f};
  float o_[4][4] = {};
  for (int kt=0; kt<32; kt++){
    const size_t kb = (size_t)(tb + kt*64);
    __syncthreads();   // prev PV done; safe to overwrite Ks/Vs (and later Ps)
    #pragma unroll
    for (int it=0; it<4; it++){
      const int d = sl + 16*it;
      float v0 = qkv[(kb+sg+0)*3072 + 1024 + go + d];
      float v1 = qkv[(kb+sg+1)*3072 + 1024 + go + d];
      float v2 = qkv[(kb+sg+2)*3072 + 1024 + go + d];
      float v3 = qkv[(kb+sg+3)*3072 + 1024 + go + d];
      *(float4*)&Ks[d*72 + (((sg>>2) ^ (d&15))<<2)] = make_float4(v0,v1,v2,v3);
      const int c = t + 256*it; const int vr = c>>4, vdc = (c&15)*4;
      *(float4*)&Vs[vr*72 + vdc] = *(const float4*)&qkv[(kb+vr)*3072 + 2048 + go + vdc];
    }
    __syncthreads();
    // scores: 4x4 per thread over (q=qi*4.., key=kj*4..)
    float s_[4][4] = {};
    #pragma unroll 8
    for (int d=0; d<64; d++){
      const float4 qa4 = *(const float4*)&Qs[d*72 + ((qi ^ (d&15))<<2)];
      const float4 kb4 = *(const float4*)&Ks[d*72 + ((kj ^ (d&15))<<2)];
      float qa[4]={qa4.x,qa4.y,qa4.z,qa4.w}, kv[4]={kb4.x,kb4.y,kb4.z,kb4.w};
      #pragma unroll
      for (int i=0;i<4;i++)
        #pragma unroll
        for (int j=0;j<4;j++) s_[i][j] = fmaf(qa[i], kv[j], s_[i][j]);
    }
    // online softmax (rows reduce across the 16 kj lanes)
    float scale_[4];
    #pragma unroll
    for (int i=0;i<4;i++){
      float mx = fmaxf(fmaxf(s_[i][0],s_[i][1]), fmaxf(s_[i][2],s_[i][3]));
      mx = fmaxf(mx, __shfl_xor(mx,1)); mx = fmaxf(mx, __shfl_xor(mx,2));
      mx = fmaxf(mx, __shfl_xor(mx,4)); mx = fmaxf(mx, __shfl_xor(mx,8));
      const float mn = fmaxf(m_[i], mx);
      scale_[i] = __expf(m_[i] - mn);
      m_[i] = mn;
      float rs = 0.f;
      #pragma unroll
      for (int j=0;j<4;j++){ s_[i][j] = __expf(s_[i][j]-mn); rs += s_[i][j]; }
      rs += __shfl_xor(rs,1); rs += __shfl_xor(rs,2);
      rs += __shfl_xor(rs,4); rs += __shfl_xor(rs,8);
      l_[i] = l_[i]*scale_[i] + rs;
    }
    #pragma unroll
    for (int i=0;i<4;i++)
      *(float4*)&Ps[(qi*4+i)*72 + kj*4] = make_float4(s_[i][0],s_[i][1],s_[i][2],s_[i][3]);
    #pragma unroll
    for (int i=0;i<4;i++)
      #pragma unroll
      for (int j=0;j<4;j++) o_[i][j] *= scale_[i];
    __syncthreads();   // Ps fully written
    // PV: thread covers (q=qi*4.., d=kj*4..)
    #pragma unroll 4
    for (int k4=0; k4<64; k4+=4){
      float pr[4][4], vv[4][4];
      #pragma unroll
      for (int i=0;i<4;i++){
        const float4 p4 = *(const float4*)&Ps[(qi*4+i)*72 + k4];
        pr[i][0]=p4.x; pr[i][1]=p4.y; pr[i][2]=p4.z; pr[i][3]=p4.w;
      }
      #pragma unroll
      for (int j2=0;j2<4;j2++){
        const float4 v4 = *(const float4*)&Vs[(k4+j2)*72 + kj*4];
        vv[j2][0]=v4.x; vv[j2][1]=v4.y; vv[j2][2]=v4.z; vv[j2][3]=v4.w;
      }
      #pragma unroll
      for (int i=0;i<4;i++)
        #pragma unroll
        for (int j2=0;j2<4;j2++)
          #pragma unroll
          for (int j=0;j<4;j++) o_[i][j] = fmaf(pr[i][j2], vv[j2][j], o_[i][j]);
    }
  }
  #pragma unroll
  for (int i=0;i<4;i++){
    const float inv = 1.f/l_[i];
    *(float4*)&ctx[(size_t)(tb+q0+qi*4+i)*1024 + go + kj*4] =
      make_float4(o_[i][0]*inv, o_[i][1]*inv, o_[i][2]*inv, o_[i][3]*inv);
  }
}

// ---------------------------------------------------------------------------
// LayerNorm (f32 in -> f32 out), one row per block
// ---------------------------------------------------------------------------
__global__ __launch_bounds__(256) void ln_kernel(const float* __restrict__ in,
    const float* __restrict__ g, const float* __restrict__ b, float* __restrict__ o)
{
  const int r = blockIdx.x, t = threadIdx.x;
  const float4 v = *(const float4*)&in[(size_t)r*1024 + t*4];
  float s = v.x+v.y+v.z+v.w;
  float q = v.x*v.x + v.y*v.y + v.z*v.z + v.w*v.w;
  #pragma unroll
  for (int off=1; off<64; off<<=1){ s += __shfl_xor(s,off); q += __shfl_xor(q,off); }
  __shared__ float red[8];
  const int w = t>>6, lane = t&63;
  if (lane==0){ red[w]=s; red[4+w]=q; }
  __syncthreads();
  s = red[0]+red[1]+red[2]+red[3];
  q = red[4]+red[5]+red[6]+red[7];
  const float mu = s*(1.f/1024.f);
  const float var = q*(1.f/1024.f) - mu*mu;
  const float rstd = rsqrtf(var + 1e-5f);
  const float4 gv = *(const float4*)&g[t*4];
  const float4 bv = *(const float4*)&b[t*4];
  *(float4*)&o[(size_t)r*1024 + t*4] = make_float4(
    (v.x-mu)*rstd*gv.x + bv.x, (v.y-mu)*rstd*gv.y + bv.y,
    (v.z-mu)*rstd*gv.z + bv.z, (v.w-mu)*rstd*gv.w + bv.w);
}

// ---------------------------------------------------------------------------
// gate: fp32 logits, top-2 (jax tie-break = lowest index), softmax probs, counts
// ---------------------------------------------------------------------------
__global__ __launch_bounds__(256) void gate_kernel(
    const float* __restrict__ xf, const float* __restrict__ gw, const float* __restrict__ gb,
    float* __restrict__ glog, int* __restrict__ top2e,
    float* __restrict__ p0a, float* __restrict__ p1a, int* __restrict__ counts)
{
  const int tok  = blockIdx.x*4 + (threadIdx.x>>6);
  const int lane = threadIdx.x & 63;
  float part[8] = {};
  const float* xr = xf + (size_t)tok*1024;
  #pragma unroll
  for (int kk=0; kk<16; kk++){
    const int d = kk*64 + lane;
    const float xv = xr[d];
    #pragma unroll
    for (int e=0;e<8;e++) part[e] = fmaf(xv, gw[e*1024+d], part[e]);
  }
  #pragma unroll
  for (int e=0;e<8;e++){
    float s = part[e];
    s += __shfl_xor(s,1); s += __shfl_xor(s,2); s += __shfl_xor(s,4);
    s += __shfl_xor(s,8); s += __shfl_xor(s,16); s += __shfl_xor(s,32);
    part[e] = s + gb[e];
  }
  if (lane==0){
    #pragma unroll
    for (int e=0;e<8;e++) glog[(size_t)tok*8+e] = part[e];
    float v0=-1e30f; int e0=0;
    #pragma unroll
    for (int e=0;e<8;e++) if (part[e] > v0){ v0=part[e]; e0=e; }
    float v1=-1e30f; int e1=0;
    #pragma unroll
    for (int e=0;e<8;e++) if (e!=e0 && part[e] > v1){ v1=part[e]; e1=e; }
    const float p0 = 1.f/(1.f + __expf(v1-v0));
    top2e[tok] = e0 | (e1<<4);
    p0a[tok] = p0; p1a[tok] = 1.f - p0;
    atomicAdd(&counts[e0],1); atomicAdd(&counts[e1],1);
  }
}

__global__ void route_offsets_kernel(const int* __restrict__ counts, int* __restrict__ offs,
                                     int* __restrict__ cursors, int* __restrict__ rowmap)
{
  const int t = threadIdx.x;
  if (t==0){
    int a=0;
    for (int e=0;e<8;e++){ offs[e]=a; a += (counts[e]+127)&~127; }
    offs[8]=a;
  }
  if (t<8) cursors[t]=0;
  for (int i=t;i<MPAD;i+=256) rowmap[i] = -1;
}

__global__ void route_assign_kernel(const int* __restrict__ top2e, const int* __restrict__ offs,
    int* __restrict__ cursors, int* __restrict__ rowmap, int* __restrict__ tokslot)
{
  const int tok = blockIdx.x*256 + threadIdx.x;
  const int pk = top2e[tok];
  const int e0 = pk & 15, e1 = pk >> 4;
  const int s0 = offs[e0] + atomicAdd(&cursors[e0], 1);
  const int s1 = offs[e1] + atomicAdd(&cursors[e1], 1);
  rowmap[s0] = tok; rowmap[s1] = tok;
  tokslot[2*tok] = s0; tokslot[2*tok+1] = s1;
}

__global__ __launch_bounds__(256) void gather_kernel(const int* __restrict__ rowmap,
    const float* __restrict__ xf, u16* __restrict__ xg)
{
  const int slot = blockIdx.x, t = threadIdx.x;
  u16* dst = xg + (size_t)slot*1024;
  const int r = rowmap[slot];
  if (r >= 0){
    const float4 v = *(const float4*)&xf[(size_t)r*1024 + t*4];
    uint2 p; p.x = (u32)f2b(v.x) | ((u32)f2b(v.y)<<16);
             p.y = (u32)f2b(v.z) | ((u32)f2b(v.w)<<16);
    *(uint2*)&dst[t*4] = p;
  } else {
    uint2 z; z.x=0u; z.y=0u;
    *(uint2*)&dst[t*4] = z;
  }
}

// ---------------------------------------------------------------------------
// MoE expert GEMM, bf16 MFMA 16x16x32. 128x128 tile, BK=32, 4 waves (2x2 of 64x64).
// A: bf16 [MPAD,K]; W: fp32 per-expert [N,K] converted to bf16 during staging.
// EPI 0: relu(acc + b1[e]) -> h ; EPI 1: acc + b2[e] -> y
// ---------------------------------------------------------------------------
template<int KDIM, int EPI>
__global__ __launch_bounds__(256,2) void gemm_moe_kernel(
    const u16* __restrict__ A, const float* __restrict__ Wbase,
    const float* __restrict__ biasbase, u16* __restrict__ C,
    const int* __restrict__ offs, int N)
{
  constexpr int LS = 56;  // LDS row stride (elems): 112B -> 16B-aligned, ~conflict-free
  __shared__ u16 As[128*LS];
  __shared__ u16 Bs[128*LS];
  const int m0 = blockIdx.y*128, n0 = blockIdx.x*128;
  int e = 0;
  #pragma unroll
  for (int i=1;i<8;i++) if (offs[i] <= m0) e = i;
  const float* W    = Wbase + (size_t)e*N*KDIM;
  const float* bias = biasbase + (size_t)e*N;
  const int t = threadIdx.x;
  const int w = t>>6, lane = t&63;
  const int wr = (w>>1)*64, wc = (w&1)*64;
  const int lr = lane&15, lk = (lane>>4)*8;
  const int ar = t>>2, ac8 = (t&3)*8;   // A staging: uint4 (8 bf16), 2 iters
  const int br = t>>3, bc4 = (t&7)*4;   // B staging: float4 -> 4 bf16, 4 iters
  f32x4 acc[4][4];
  #pragma unroll
  for (int mi=0;mi<4;mi++)
    #pragma unroll
    for (int ni=0;ni<4;ni++){ acc[mi][ni][0]=0.f; acc[mi][ni][1]=0.f; acc[mi][ni][2]=0.f; acc[mi][ni][3]=0.f; }
  for (int k0=0; k0<KDIM; k0+=32){
    __syncthreads();
    #pragma unroll
    for (int it=0; it<2; it++){
      const int r = ar + it*64;
      *(uint4*)&As[r*LS + ac8] = *(const uint4*)&A[(size_t)(m0+r)*KDIM + k0 + ac8];
    }
    #pragma unroll
    for (int it=0; it<4; it++){
      const int r = br + it*32;
      const float4 v = *(const float4*)&W[(size_t)(n0+r)*KDIM + k0 + bc4];
      uint2 p; p.x = (u32)f2b(v.x) | ((u32)f2b(v.y)<<16);
               p.y = (u32)f2b(v.z) | ((u32)f2b(v.w)<<16);
      *(uint2*)&Bs[r*LS + bc4] = p;
    }
    __syncthreads();
    bf16x8 af[4], bfr[4];
    #pragma unroll
    for (int mi=0;mi<4;mi++) af[mi]  = *(const bf16x8*)&As[(wr+mi*16+lr)*LS + lk];
    #pragma unroll
    for (int ni=0;ni<4;ni++) bfr[ni] = *(const bf16x8*)&Bs[(wc+ni*16+lr)*LS + lk];
    #pragma unroll
    for (int mi=0;mi<4;mi++)
      #pragma unroll
      for (int ni=0;ni<4;ni++)
        acc[mi][ni] = __builtin_amdgcn_mfma_f32_16x16x32_bf16(af[mi], bfr[ni], acc[mi][ni], 0,0,0);
  }
  const int lr4 = (lane>>4)*4, lc = lane&15;
  #pragma unroll
  for (int mi=0;mi<4;mi++)
    #pragma unroll
    for (int ni=0;ni<4;ni++){
      const int gn = n0 + wc + ni*16 + lc;
      const float be = bias[gn];
      #pragma unroll
      for (int j=0;j<4;j++){
        const int gm = m0 + wr + mi*16 + lr4 + j;
        float v = acc[mi][ni][j] + be;
        if (EPI==0) v = fmaxf(v, 0.f);
        C[(size_t)gm*N + gn] = f2b(v);
      }
    }
}

// ---------------------------------------------------------------------------
// combine top-2 expert outputs + residual + LN2 -> final output (f32)
// ---------------------------------------------------------------------------
__global__ __launch_bounds__(256) void combine_ln2_kernel(
    const float* __restrict__ xf, const u16* __restrict__ y, const int* __restrict__ tokslot,
    const float* __restrict__ p0a, const float* __restrict__ p1a,
    const float* __restrict__ g, const float* __restrict__ b, float* __restrict__ o)
{
  const int tok = blockIdx.x, t = threadIdx.x;
  const int s0 = tokslot[2*tok], s1 = tokslot[2*tok+1];
  const float w0 = p0a[tok], w1 = p1a[tok];
  const float4 xv = *(const float4*)&xf[(size_t)tok*1024 + t*4];
  const uint2 ya = *(const uint2*)&y[(size_t)s0*1024 + t*4];
  const uint2 yb = *(const uint2*)&y[(size_t)s1*1024 + t*4];
  const float va[4] = {b2f((u16)(ya.x&0xFFFF)), b2f((u16)(ya.x>>16)),
                       b2f((u16)(ya.y&0xFFFF)), b2f((u16)(ya.y>>16))};
  const float vb[4] = {b2f((u16)(yb.x&0xFFFF)), b2f((u16)(yb.x>>16)),
                       b2f((u16)(yb.y&0xFFFF)), b2f((u16)(yb.y>>16))};
  const float xe[4] = {xv.x, xv.y, xv.z, xv.w};
  float vv[4];
  #pragma unroll
  for (int i=0;i<4;i++) vv[i] = xe[i] + w0*va[i] + w1*vb[i];
  float s = vv[0]+vv[1]+vv[2]+vv[3];
  float q = vv[0]*vv[0]+vv[1]*vv[1]+vv[2]*vv[2]+vv[3]*vv[3];
  #pragma unroll
  for (int off=1; off<64; off<<=1){ s += __shfl_xor(s,off); q += __shfl_xor(q,off); }
  __shared__ float red[8];
  const int w = t>>6, lane = t&63;
  if (lane==0){ red[w]=s; red[4+w]=q; }
  __syncthreads();
  s = red[0]+red[1]+red[2]+red[3];
  q = red[4]+red[5]+red[6]+red[7];
  const float mu = s*(1.f/1024.f);
  const float var = q*(1.f/1024.f) - mu*mu;
  const float rstd = rsqrtf(var + 1e-5f);
  const float4 gv = *(const float4*)&g[t*4];
  const float4 bv = *(const float4*)&b[t*4];
  *(float4*)&o[(size_t)tok*1024 + t*4] = make_float4(
    (vv[0]-mu)*rstd*gv.x + bv.x, (vv[1]-mu)*rstd*gv.y + bv.y,
    (vv[2]-mu)*rstd*gv.z + bv.z, (vv[3]-mu)*rstd*gv.w + bv.w);
}

// ---------------------------------------------------------------------------
extern "C" void kernel_launch(void* const* d_in, const int* in_sizes, int n_in,
                              void* d_out, int out_size, void* d_ws, size_t ws_size,
                              hipStream_t stream)
{
  const float* src  = (const float*)d_in[0];
  const float* inw  = (const float*)d_in[1];
  const float* inb  = (const float*)d_in[2];
  const float* ow   = (const float*)d_in[3];
  const float* ob   = (const float*)d_in[4];
  const float* ln1g = (const float*)d_in[5];
  const float* ln1b = (const float*)d_in[6];
  const float* gw   = (const float*)d_in[7];
  const float* gb   = (const float*)d_in[8];
  const float* w1   = (const float*)d_in[9];
  const float* b1   = (const float*)d_in[10];
  const float* w2   = (const float*)d_in[11];
  const float* b2   = (const float*)d_in[12];
  const float* ln2g = (const float*)d_in[13];
  const float* ln2b = (const float*)d_in[14];

  float* out  = (float*)d_out;
  float* glog = out + (size_t)TT*DM;

  char* ws = (char*)d_ws;
  float* qkvf    = (float*)(ws + OFF_R0);            // [T,3072] f32
  float* attnout = (float*)(ws + OFF_R0);            // [T,1024] f32 (after attn)
  u16*   hbuf    = (u16*)  (ws + OFF_R0);            // [MPAD,4096] bf16 (after LN1)
  float* ctxf    = (float*)(ws + OFF_R1);            // [T,1024] f32
  u16*   ybuf    = (u16*)  (ws + OFF_R1);            // [MPAD,1024] bf16 (after out-proj)
  float* xf      = (float*)(ws + OFF_R2);            // [T,1024] f32
  u16*   xg      = (u16*)  (ws + OFF_R3);            // [MPAD,1024] bf16
  int*   top2e   = (int*)  (ws + OFF_RT);
  float* p0a     = (float*)(ws + OFF_RT + 32768);
  float* p1a     = (float*)(ws + OFF_RT + 65536);
  int*   counts  = (int*)  (ws + OFF_RT + 98304);
  int*   offs    = (int*)  (ws + OFF_RT + 98336);
  int*   cursors = (int*)  (ws + OFF_RT + 98400);
  int*   rowmap  = (int*)  (ws + OFF_RT + 98432);
  int*   tokslot = (int*)  (ws + OFF_RT + 168064);

  hipMemsetAsync(counts, 0, 8*sizeof(int), stream);

  // QKV projection (fp32): [8192,1024]@[3072,1024]^T
  gemm_f32_kernel<0><<<dim3(48,128),256,0,stream>>>(src, inw, inb, nullptr, qkvf, 1024, 3072);
  // flash attention (fp32)
  attn_kernel<<<dim3(32,64),256,0,stream>>>(qkvf, ctxf);
  // out projection + residual (fp32)
  gemm_f32_kernel<1><<<dim3(16,128),256,0,stream>>>(ctxf, ow, ob, src, attnout, 1024, 1024);
  // LN1 -> x (f32)
  ln_kernel<<<8192,256,0,stream>>>(attnout, ln1g, ln1b, xf);
  // gate + top2 + counts (fp32)
  gate_kernel<<<2048,256,0,stream>>>(xf, gw, gb, glog, top2e, p0a, p1a, counts);
  // routing bookkeeping
  route_offsets_kernel<<<1,256,0,stream>>>(counts, offs, cursors, rowmap);
  route_assign_kernel<<<32,256,0,stream>>>(top2e, offs, cursors, rowmap, tokslot);
  // gather x rows (bf16) into per-expert segments
  gather_kernel<<<MPAD,256,0,stream>>>(rowmap, xf, xg);
  // expert FFN (bf16 MFMA)
  gemm_moe_kernel<1024,0><<<dim3(32,136),256,0,stream>>>(xg, w1, b1, hbuf, offs, DHID);
  gemm_moe_kernel<4096,1><<<dim3(8,136),256,0,stream>>>(hbuf, w2, b2, ybuf, offs, DM);
  // combine + LN2 -> out
  combine_ln2_kernel<<<8192,256,0,stream>>>(xf, ybuf, tokslot, p0a, p1a, ln2g, ln2b, out);
}

// Round 2
// 1821.311 us; speedup vs baseline: 1.7297x; 1.7297x over previous
//
#include <hip/hip_runtime.h>
#include <cstdint>

#define DEV static __device__ __forceinline__

typedef unsigned short u16;
typedef unsigned int   u32;
typedef __attribute__((ext_vector_type(8))) short bf16x8;
typedef __attribute__((ext_vector_type(8))) _Float16 f16x8;
typedef __attribute__((ext_vector_type(4))) float f32x4;

constexpr int TT   = 8192;   // tokens = 4*2048
constexpr int DM   = 1024;
constexpr int DHID = 4096;
constexpr int MPAD = 17408;  // 136 * 128 (worst-case padded routed rows)

// ---- ws layout (bytes) ----
constexpr size_t OFF_R0 = 0;            // h bf16 [MPAD][4096]; earlier hosts qkv_f32 then attn_out f32
constexpr size_t OFF_R1 = 142606336;    // ctx f32 [T][1024] then y bf16 [MPAD][1024]
constexpr size_t OFF_R2 = 178257920;    // x f32 (LN1 out)
constexpr size_t OFF_R3 = 211812352;    // xg bf16 [MPAD][1024]
constexpr size_t OFF_RT = 247463936;    // routing scratch

DEV u16 f2b(float f){ u32 b = __builtin_bit_cast(u32, f); return (u16)((b + 0x7FFFu + ((b>>16)&1u))>>16); }
DEV float b2f(u16 u){ u32 b = ((u32)u)<<16; return __builtin_bit_cast(float, b); }

// split x,y into fp16 hi + (fp16 lo scaled by 1024); pack pairs into u32
DEV void split2(float x, float y, u32& hi, u32& lo){
  _Float16 hx = (_Float16)x, hy = (_Float16)y;
  float rx = (x - (float)hx)*1024.f, ry = (y - (float)hy)*1024.f;
  _Float16 lx = (_Float16)rx, ly = (_Float16)ry;
  hi = (u32)__builtin_bit_cast(u16,hx) | ((u32)__builtin_bit_cast(u16,hy)<<16);
  lo = (u32)__builtin_bit_cast(u16,lx) | ((u32)__builtin_bit_cast(u16,ly)<<16);
}

// stage 16 consecutive f32 (src[c0..c0+15], scaled) into hi/lo LDS row r
// LDS rows are 64 halfs (128B) with 16B-chunk XOR swizzle: chunk' = chunk ^ (r&7)
DEV void stage16(const float* __restrict__ src, u16* hiB, u16* loB, int r, int c0, float scale){
  float4 v[4];
  #pragma unroll
  for (int j=0;j<4;j++) v[j] = *(const float4*)(src + c0 + 4*j);
  #pragma unroll
  for (int j=0;j<4;j++){ v[j].x*=scale; v[j].y*=scale; v[j].z*=scale; v[j].w*=scale; }
  u32 h[8], lo8[8];
  split2(v[0].x, v[0].y, h[0], lo8[0]); split2(v[0].z, v[0].w, h[1], lo8[1]);
  split2(v[1].x, v[1].y, h[2], lo8[2]); split2(v[1].z, v[1].w, h[3], lo8[3]);
  split2(v[2].x, v[2].y, h[4], lo8[4]); split2(v[2].z, v[2].w, h[5], lo8[5]);
  split2(v[3].x, v[3].y, h[6], lo8[6]); split2(v[3].z, v[3].w, h[7], lo8[7]);
  const int cb = c0>>3;
  const int i0 = r*64 + (((cb+0) ^ (r&7))<<3);
  const int i1 = r*64 + (((cb+1) ^ (r&7))<<3);
  *(uint4*)&hiB[i0] = make_uint4(h[0],h[1],h[2],h[3]);
  *(uint4*)&hiB[i1] = make_uint4(h[4],h[5],h[6],h[7]);
  *(uint4*)&loB[i0] = make_uint4(lo8[0],lo8[1],lo8[2],lo8[3]);
  *(uint4*)&loB[i1] = make_uint4(lo8[4],lo8[5],lo8[6],lo8[7]);
}

// ---------------------------------------------------------------------------
// split-fp16 MFMA GEMM: C[M,N] = A[M,K] @ W[N,K]^T + bias (+resid), fp32 in/out.
// 128x64 tile, BK=64, 4 waves (2x2), per-wave 64x32 (4x2 frags of 16x16x32).
// acc = acc_hihi + acc_cross * 2^-10  (rel err ~2^-19: routing-safe)
// ---------------------------------------------------------------------------
template<int RESID>
__global__ __launch_bounds__(256,2) void gemm_f16x2_kernel(
    const float* __restrict__ A, const float* __restrict__ W,
    const float* __restrict__ bias, const float* __restrict__ resid,
    float* __restrict__ C, int K, int N)
{
  __shared__ __align__(16) u16 sm[24576];
  u16* Ahi = sm;          u16* Alo = sm + 8192;
  u16* Bhi = sm + 16384;  u16* Blo = sm + 20480;
  const int m0 = blockIdx.y*128, n0 = blockIdx.x*64;
  const int t = threadIdx.x, l = t&63, w = t>>6;
  const int lr = l&15, lg = l>>4;
  const int wr = (w>>1)*64, wc = (w&1)*32;
  const int ar = t>>1, ac0 = (t&1)*32;
  const int br = t>>2, bc0 = (t&3)*16;
  f32x4 a0[4][2], a1[4][2];
  #pragma unroll
  for (int m=0;m<4;m++)
    #pragma unroll
    for (int n=0;n<2;n++){ a0[m][n]=(f32x4){0,0,0,0}; a1[m][n]=(f32x4){0,0,0,0}; }
  const float* Arow = A + (size_t)(m0+ar)*K;
  const float* Wrow = W + (size_t)(n0+br)*K;
  for (int k0=0; k0<K; k0+=64){
    __syncthreads();
    stage16(Arow + k0, Ahi, Alo, ar, ac0,      1.f);
    stage16(Arow + k0, Ahi, Alo, ar, ac0 + 16, 1.f);
    stage16(Wrow + k0, Bhi, Blo, br, bc0,      1.f);
    __syncthreads();
    #pragma unroll
    for (int s=0;s<2;s++){
      f16x8 bh[2], bl[2];
      #pragma unroll
      for (int n=0;n<2;n++){
        const int bi = (wc+16*n+lr)*64 + ((32*s + 8*lg) ^ ((lr&7)<<3));
        bh[n] = *(const f16x8*)&Bhi[bi];
        bl[n] = *(const f16x8*)&Blo[bi];
      }
      #pragma unroll
      for (int m=0;m<4;m++){
        const int ai = (wr+16*m+lr)*64 + ((32*s + 8*lg) ^ ((lr&7)<<3));
        const f16x8 ah = *(const f16x8*)&Ahi[ai];
        const f16x8 al = *(const f16x8*)&Alo[ai];
        #pragma unroll
        for (int n=0;n<2;n++){
          a0[m][n] = __builtin_amdgcn_mfma_f32_16x16x32_f16(ah, bh[n], a0[m][n], 0,0,0);
          a1[m][n] = __builtin_amdgcn_mfma_f32_16x16x32_f16(ah, bl[n], a1[m][n], 0,0,0);
          a1[m][n] = __builtin_amdgcn_mfma_f32_16x16x32_f16(al, bh[n], a1[m][n], 0,0,0);
        }
      }
    }
  }
  #pragma unroll
  for (int m=0;m<4;m++)
    #pragma unroll
    for (int n=0;n<2;n++){
      const int gn = n0 + wc + 16*n + lr;
      const float be = bias[gn];
      #pragma unroll
      for (int r=0;r<4;r++){
        const int gm = m0 + wr + 16*m + 4*lg + r;
        float v = a0[m][n][r] + a1[m][n][r]*9.765625e-4f + be;
        if (RESID) v += resid[(size_t)gm*N + gn];
        C[(size_t)gm*N + gn] = v;
      }
    }
}

// ---------------------------------------------------------------------------
// split-fp16 MFMA flash attention. grid (32 qtiles, 64 b*h), 256 thr (4 waves).
// Swapped QK^T (S^T = K·Q^T) so softmax is lane-local; V staged transposed;
// all LDS tiles 64-half rows + chunk^(row&7) swizzle. rel err ~2^-19.
// ---------------------------------------------------------------------------
__global__ __launch_bounds__(256,2) void attn_mfma_kernel(
    const float* __restrict__ qkv, float* __restrict__ ctx)
{
  __shared__ __align__(16) u16 sm[24576];
  u16* Khi = sm;          u16* Klo = sm + 4096;
  u16* Vhi = sm + 8192;   u16* Vlo = sm + 12288;
  u16* Phi = sm + 16384;  u16* Plo = sm + 20480;
  float* fsm = (float*)sm;
  const int bh = blockIdx.y, bb = bh>>4, h = bh&15;
  const int tb = bb*2048, q0 = blockIdx.x*64, go = h*64;
  const int t = threadIdx.x, l = t&63, w = t>>6;
  const int lr = l&15, lg = l>>4;
  const int sr = t>>2, sc0 = (t&3)*16;

  // stage Q (scaled by 1/8) into Phi/Plo, hoist per-wave Q frags to regs
  stage16(qkv + (size_t)(tb+q0+sr)*3072 + go, Phi, Plo, sr, sc0, 0.125f);
  __syncthreads();
  f16x8 qh[2], ql[2];
  #pragma unroll
  for (int s=0;s<2;s++){
    const int qi = (16*w+lr)*64 + ((32*s + 8*lg) ^ ((lr&7)<<3));
    qh[s] = *(const f16x8*)&Phi[qi];
    ql[s] = *(const f16x8*)&Plo[qi];
  }

  float m_ = -1e30f, l_ = 0.f;
  f32x4 c0a[4], c1a[4];
  #pragma unroll
  for (int m=0;m<4;m++){ c0a[m]=(f32x4){0,0,0,0}; c1a[m]=(f32x4){0,0,0,0}; }

  for (int kt=0; kt<32; ++kt){
    const size_t kb = (size_t)(tb + kt*64);
    __syncthreads();     // prev tile's PV done -> K/V/P LDS free
    // stage K rows [key][d]
    stage16(qkv + (kb+sr)*3072 + 1024 + go, Khi, Klo, sr, sc0, 1.f);
    // stage V transposed [d][key]: lane owns column d = l, wave owns 16 keys
    {
      const int d = l;
      u32 vh[8], vlo[8];
      #pragma unroll
      for (int j=0;j<8;j++){
        const float f0 = qkv[(kb + w*16 + 2*j    )*3072 + 2048 + go + d];
        const float f1 = qkv[(kb + w*16 + 2*j + 1)*3072 + 2048 + go + d];
        split2(f0, f1, vh[j], vlo[j]);
      }
      const int i0 = d*64 + ((16*w + 0) ^ ((d&7)<<3));
      const int i1 = d*64 + ((16*w + 8) ^ ((d&7)<<3));
      *(uint4*)&Vhi[i0] = make_uint4(vh[0],vh[1],vh[2],vh[3]);
      *(uint4*)&Vhi[i1] = make_uint4(vh[4],vh[5],vh[6],vh[7]);
      *(uint4*)&Vlo[i0] = make_uint4(vlo[0],vlo[1],vlo[2],vlo[3]);
      *(uint4*)&Vlo[i1] = make_uint4(vlo[4],vlo[5],vlo[6],vlo[7]);
    }
    __syncthreads();
    // S^T = K·Q^T : D[key][q], wave w owns q-slice 16w..16w+15
    f32x4 s0[4], s1[4];
    #pragma unroll
    for (int m=0;m<4;m++){ s0[m]=(f32x4){0,0,0,0}; s1[m]=(f32x4){0,0,0,0}; }
    #pragma unroll
    for (int s=0;s<2;s++){
      #pragma unroll
      for (int m=0;m<4;m++){
        const int ai = (16*m+lr)*64 + ((32*s + 8*lg) ^ ((lr&7)<<3));
        const f16x8 ah = *(const f16x8*)&Khi[ai];
        const f16x8 al = *(const f16x8*)&Klo[ai];
        s0[m] = __builtin_amdgcn_mfma_f32_16x16x32_f16(ah, qh[s], s0[m], 0,0,0);
        s1[m] = __builtin_amdgcn_mfma_f32_16x16x32_f16(ah, ql[s], s1[m], 0,0,0);
        s1[m] = __builtin_amdgcn_mfma_f32_16x16x32_f16(al, qh[s], s1[m], 0,0,0);
      }
    }
    // online softmax: lane holds 16 keys (4 frags x 4 regs) for q = 16w+lr;
    // full 64-key reduce via local + shfl_xor(16,32) (lanes l,l+16,l+32,l+48 share q)
    float p[4][4];
    float mx = -1e30f;
    #pragma unroll
    for (int m=0;m<4;m++)
      #pragma unroll
      for (int r=0;r<4;r++){
        const float v = s0[m][r] + s1[m][r]*9.765625e-4f;
        p[m][r] = v; mx = fmaxf(mx, v);
      }
    mx = fmaxf(mx, __shfl_xor(mx,16));
    mx = fmaxf(mx, __shfl_xor(mx,32));
    const float mn = fmaxf(m_, mx);
    const float sc = __expf(m_ - mn);
    float rs = 0.f;
    #pragma unroll
    for (int m=0;m<4;m++)
      #pragma unroll
      for (int r=0;r<4;r++){ const float e = __expf(p[m][r]-mn); p[m][r]=e; rs += e; }
    rs += __shfl_xor(rs,16);
    rs += __shfl_xor(rs,32);
    l_ = l_*sc + rs; m_ = mn;
    #pragma unroll
    for (int m=0;m<4;m++){ c0a[m] *= sc; c1a[m] *= sc; }
    // write P [q][key] hi/lo (own wave's rows only)
    const int prow = 16*w + lr;
    #pragma unroll
    for (int m=0;m<4;m++){
      u32 h0,l0,h1,l1;
      split2(p[m][0], p[m][1], h0, l0);
      split2(p[m][2], p[m][3], h1, l1);
      const int pi = prow*64 + ((16*m + 4*lg) ^ ((lr&7)<<3));
      *(uint2*)&Phi[pi] = make_uint2(h0,h1);
      *(uint2*)&Plo[pi] = make_uint2(l0,l1);
    }
    // PV: ctx^T[d][q] += V^T · P^T  (A = VT rows d, B = P rows q)
    #pragma unroll
    for (int s=0;s<2;s++){
      const int bi = prow*64 + ((32*s + 8*lg) ^ ((lr&7)<<3));
      const f16x8 ph = *(const f16x8*)&Phi[bi];
      const f16x8 pl = *(const f16x8*)&Plo[bi];
      #pragma unroll
      for (int m=0;m<4;m++){
        const int ai = (16*m+lr)*64 + ((32*s + 8*lg) ^ ((lr&7)<<3));
        const f16x8 vh8 = *(const f16x8*)&Vhi[ai];
        const f16x8 vl8 = *(const f16x8*)&Vlo[ai];
        c0a[m] = __builtin_amdgcn_mfma_f32_16x16x32_f16(vh8, ph, c0a[m], 0,0,0);
        c1a[m] = __builtin_amdgcn_mfma_f32_16x16x32_f16(vh8, pl, c1a[m], 0,0,0);
        c1a[m] = __builtin_amdgcn_mfma_f32_16x16x32_f16(vl8, ph, c1a[m], 0,0,0);
      }
    }
  }
  // epilogue: normalize, transpose through LDS (f32 [64][68]), coalesced store
  __syncthreads();
  {
    const float inv = 1.f/l_;
    const int q = 16*w + lr;
    #pragma unroll
    for (int m=0;m<4;m++)
      #pragma unroll
      for (int r=0;r<4;r++)
        fsm[q*68 + 16*m + 4*lg + r] = (c0a[m][r] + c1a[m][r]*9.765625e-4f)*inv;
  }
  __syncthreads();
  #pragma unroll
  for (int j=0;j<4;j++){
    const float4 vv = *(const float4*)&fsm[sr*68 + sc0 + 4*j];
    *(float4*)&ctx[(size_t)(tb+q0+sr)*1024 + go + sc0 + 4*j] = vv;
  }
}

// ---------------------------------------------------------------------------
// LayerNorm (f32 in -> f32 out), one row per block
// ---------------------------------------------------------------------------
__global__ __launch_bounds__(256) void ln_kernel(const float* __restrict__ in,
    const float* __restrict__ g, const float* __restrict__ b, float* __restrict__ o)
{
  const int r = blockIdx.x, t = threadIdx.x;
  const float4 v = *(const float4*)&in[(size_t)r*1024 + t*4];
  float s = v.x+v.y+v.z+v.w;
  float q = v.x*v.x + v.y*v.y + v.z*v.z + v.w*v.w;
  #pragma unroll
  for (int off=1; off<64; off<<=1){ s += __shfl_xor(s,off); q += __shfl_xor(q,off); }
  __shared__ float red[8];
  const int w = t>>6, lane = t&63;
  if (lane==0){ red[w]=s; red[4+w]=q; }
  __syncthreads();
  s = red[0]+red[1]+red[2]+red[3];
  q = red[4]+red[5]+red[6]+red[7];
  const float mu = s*(1.f/1024.f);
  const float var = q*(1.f/1024.f) - mu*mu;
  const float rstd = rsqrtf(var + 1e-5f);
  const float4 gv = *(const float4*)&g[t*4];
  const float4 bv = *(const float4*)&b[t*4];
  *(float4*)&o[(size_t)r*1024 + t*4] = make_float4(
    (v.x-mu)*rstd*gv.x + bv.x, (v.y-mu)*rstd*gv.y + bv.y,
    (v.z-mu)*rstd*gv.z + bv.z, (v.w-mu)*rstd*gv.w + bv.w);
}

// ---------------------------------------------------------------------------
// gate: fp32 logits, top-2 (lowest index wins ties), softmax probs, counts
// ---------------------------------------------------------------------------
__global__ __launch_bounds__(256) void gate_kernel(
    const float* __restrict__ xf, const float* __restrict__ gw, const float* __restrict__ gb,
    float* __restrict__ glog, int* __restrict__ top2e,
    float* __restrict__ p0a, float* __restrict__ p1a, int* __restrict__ counts)
{
  const int tok  = blockIdx.x*4 + (threadIdx.x>>6);
  const int lane = threadIdx.x & 63;
  float part[8] = {};
  const float* xr = xf + (size_t)tok*1024;
  #pragma unroll
  for (int kk=0; kk<16; kk++){
    const int d = kk*64 + lane;
    const float xv = xr[d];
    #pragma unroll
    for (int e=0;e<8;e++) part[e] = fmaf(xv, gw[e*1024+d], part[e]);
  }
  #pragma unroll
  for (int e=0;e<8;e++){
    float s = part[e];
    s += __shfl_xor(s,1); s += __shfl_xor(s,2); s += __shfl_xor(s,4);
    s += __shfl_xor(s,8); s += __shfl_xor(s,16); s += __shfl_xor(s,32);
    part[e] = s + gb[e];
  }
  if (lane==0){
    #pragma unroll
    for (int e=0;e<8;e++) glog[(size_t)tok*8+e] = part[e];
    float v0=-1e30f; int e0=0;
    #pragma unroll
    for (int e=0;e<8;e++) if (part[e] > v0){ v0=part[e]; e0=e; }
    float v1=-1e30f; int e1=0;
    #pragma unroll
    for (int e=0;e<8;e++) if (e!=e0 && part[e] > v1){ v1=part[e]; e1=e; }
    const float p0 = 1.f/(1.f + __expf(v1-v0));
    top2e[tok] = e0 | (e1<<4);
    p0a[tok] = p0; p1a[tok] = 1.f - p0;
    atomicAdd(&counts[e0],1); atomicAdd(&counts[e1],1);
  }
}

__global__ void route_offsets_kernel(const int* __restrict__ counts, int* __restrict__ offs,
                                     int* __restrict__ cursors, int* __restrict__ rowmap)
{
  const int t = threadIdx.x;
  if (t==0){
    int a=0;
    for (int e=0;e<8;e++){ offs[e]=a; a += (counts[e]+127)&~127; }
    offs[8]=a;
  }
  if (t<8) cursors[t]=0;
  for (int i=t;i<MPAD;i+=256) rowmap[i] = -1;
}

__global__ void route_assign_kernel(const int* __restrict__ top2e, const int* __restrict__ offs,
    int* __restrict__ cursors, int* __restrict__ rowmap, int* __restrict__ tokslot)
{
  const int tok = blockIdx.x*256 + threadIdx.x;
  const int pk = top2e[tok];
  const int e0 = pk & 15, e1 = pk >> 4;
  const int s0 = offs[e0] + atomicAdd(&cursors[e0], 1);
  const int s1 = offs[e1] + atomicAdd(&cursors[e1], 1);
  rowmap[s0] = tok; rowmap[s1] = tok;
  tokslot[2*tok] = s0; tokslot[2*tok+1] = s1;
}

__global__ __launch_bounds__(256) void gather_kernel(const int* __restrict__ rowmap,
    const float* __restrict__ xf, u16* __restrict__ xg)
{
  const int slot = blockIdx.x, t = threadIdx.x;
  u16* dst = xg + (size_t)slot*1024;
  const int r = rowmap[slot];
  if (r >= 0){
    const float4 v = *(const float4*)&xf[(size_t)r*1024 + t*4];
    uint2 p; p.x = (u32)f2b(v.x) | ((u32)f2b(v.y)<<16);
             p.y = (u32)f2b(v.z) | ((u32)f2b(v.w)<<16);
    *(uint2*)&dst[t*4] = p;
  } else {
    uint2 z; z.x=0u; z.y=0u;
    *(uint2*)&dst[t*4] = z;
  }
}

// ---------------------------------------------------------------------------
// MoE expert GEMM, bf16 MFMA 16x16x32. 128x128 tile, BK=32, 4 waves (2x2 of 64x64).
// ---------------------------------------------------------------------------
template<int KDIM, int EPI>
__global__ __launch_bounds__(256,2) void gemm_moe_kernel(
    const u16* __restrict__ A, const float* __restrict__ Wbase,
    const float* __restrict__ biasbase, u16* __restrict__ C,
    const int* __restrict__ offs, int N)
{
  constexpr int LS = 56;
  __shared__ u16 As[128*LS];
  __shared__ u16 Bs[128*LS];
  const int m0 = blockIdx.y*128, n0 = blockIdx.x*128;
  int e = 0;
  #pragma unroll
  for (int i=1;i<8;i++) if (offs[i] <= m0) e = i;
  const float* W    = Wbase + (size_t)e*N*KDIM;
  const float* bias = biasbase + (size_t)e*N;
  const int t = threadIdx.x;
  const int w = t>>6, lane = t&63;
  const int wr = (w>>1)*64, wc = (w&1)*64;
  const int lr = lane&15, lk = (lane>>4)*8;
  const int ar = t>>2, ac8 = (t&3)*8;
  const int br = t>>3, bc4 = (t&7)*4;
  f32x4 acc[4][4];
  #pragma unroll
  for (int mi=0;mi<4;mi++)
    #pragma unroll
    for (int ni=0;ni<4;ni++){ acc[mi][ni][0]=0.f; acc[mi][ni][1]=0.f; acc[mi][ni][2]=0.f; acc[mi][ni][3]=0.f; }
  for (int k0=0; k0<KDIM; k0+=32){
    __syncthreads();
    #pragma unroll
    for (int it=0; it<2; it++){
      const int r = ar + it*64;
      *(uint4*)&As[r*LS + ac8] = *(const uint4*)&A[(size_t)(m0+r)*KDIM + k0 + ac8];
    }
    #pragma unroll
    for (int it=0; it<4; it++){
      const int r = br + it*32;
      const float4 v = *(const float4*)&W[(size_t)(n0+r)*KDIM + k0 + bc4];
      uint2 p; p.x = (u32)f2b(v.x) | ((u32)f2b(v.y)<<16);
               p.y = (u32)f2b(v.z) | ((u32)f2b(v.w)<<16);
      *(uint2*)&Bs[r*LS + bc4] = p;
    }
    __syncthreads();
    bf16x8 af[4], bfr[4];
    #pragma unroll
    for (int mi=0;mi<4;mi++) af[mi]  = *(const bf16x8*)&As[(wr+mi*16+lr)*LS + lk];
    #pragma unroll
    for (int ni=0;ni<4;ni++) bfr[ni] = *(const bf16x8*)&Bs[(wc+ni*16+lr)*LS + lk];
    #pragma unroll
    for (int mi=0;mi<4;mi++)
      #pragma unroll
      for (int ni=0;ni<4;ni++)
        acc[mi][ni] = __builtin_amdgcn_mfma_f32_16x16x32_bf16(af[mi], bfr[ni], acc[mi][ni], 0,0,0);
  }
  const int lr4 = (lane>>4)*4, lc = lane&15;
  #pragma unroll
  for (int mi=0;mi<4;mi++)
    #pragma unroll
    for (int ni=0;ni<4;ni++){
      const int gn = n0 + wc + ni*16 + lc;
      const float be = bias[gn];
      #pragma unroll
      for (int j=0;j<4;j++){
        const int gm = m0 + wr + mi*16 + lr4 + j;
        float v = acc[mi][ni][j] + be;
        if (EPI==0) v = fmaxf(v, 0.f);
        C[(size_t)gm*N + gn] = f2b(v);
      }
    }
}

// ---------------------------------------------------------------------------
// combine top-2 expert outputs + residual + LN2 -> final output (f32)
// ---------------------------------------------------------------------------
__global__ __launch_bounds__(256) void combine_ln2_kernel(
    const float* __restrict__ xf, const u16* __restrict__ y, const int* __restrict__ tokslot,
    const float* __restrict__ p0a, const float* __restrict__ p1a,
    const float* __restrict__ g, const float* __restrict__ b, float* __restrict__ o)
{
  const int tok = blockIdx.x, t = threadIdx.x;
  const int s0 = tokslot[2*tok], s1 = tokslot[2*tok+1];
  const float w0 = p0a[tok], w1 = p1a[tok];
  const float4 xv = *(const float4*)&xf[(size_t)tok*1024 + t*4];
  const uint2 ya = *(const uint2*)&y[(size_t)s0*1024 + t*4];
  const uint2 yb = *(const uint2*)&y[(size_t)s1*1024 + t*4];
  const float va[4] = {b2f((u16)(ya.x&0xFFFF)), b2f((u16)(ya.x>>16)),
                       b2f((u16)(ya.y&0xFFFF)), b2f((u16)(ya.y>>16))};
  const float vb[4] = {b2f((u16)(yb.x&0xFFFF)), b2f((u16)(yb.x>>16)),
                       b2f((u16)(yb.y&0xFFFF)), b2f((u16)(yb.y>>16))};
  const float xe[4] = {xv.x, xv.y, xv.z, xv.w};
  float vv[4];
  #pragma unroll
  for (int i=0;i<4;i++) vv[i] = xe[i] + w0*va[i] + w1*vb[i];
  float s = vv[0]+vv[1]+vv[2]+vv[3];
  float q = vv[0]*vv[0]+vv[1]*vv[1]+vv[2]*vv[2]+vv[3]*vv[3];
  #pragma unroll
  for (int off=1; off<64; off<<=1){ s += __shfl_xor(s,off); q += __shfl_xor(q,off); }
  __shared__ float red[8];
  const int w = t>>6, lane = t&63;
  if (lane==0){ red[w]=s; red[4+w]=q; }
  __syncthreads();
  s = red[0]+red[1]+red[2]+red[3];
  q = red[4]+red[5]+red[6]+red[7];
  const float mu = s*(1.f/1024.f);
  const float var = q*(1.f/1024.f) - mu*mu;
  const float rstd = rsqrtf(var + 1e-5f);
  const float4 gv = *(const float4*)&g[t*4];
  const float4 bv = *(const float4*)&b[t*4];
  *(float4*)&o[(size_t)tok*1024 + t*4] = make_float4(
    (vv[0]-mu)*rstd*gv.x + bv.x, (vv[1]-mu)*rstd*gv.y + bv.y,
    (vv[2]-mu)*rstd*gv.z + bv.z, (vv[3]-mu)*rstd*gv.w + bv.w);
}

// ---------------------------------------------------------------------------
extern "C" void kernel_launch(void* const* d_in, const int* in_sizes, int n_in,
                              void* d_out, int out_size, void* d_ws, size_t ws_size,
                              hipStream_t stream)
{
  const float* src  = (const float*)d_in[0];
  const float* inw  = (const float*)d_in[1];
  const float* inb  = (const float*)d_in[2];
  const float* ow   = (const float*)d_in[3];
  const float* ob   = (const float*)d_in[4];
  const float* ln1g = (const float*)d_in[5];
  const float* ln1b = (const float*)d_in[6];
  const float* gw   = (const float*)d_in[7];
  const float* gb   = (const float*)d_in[8];
  const float* w1   = (const float*)d_in[9];
  const float* b1   = (const float*)d_in[10];
  const float* w2   = (const float*)d_in[11];
  const float* b2   = (const float*)d_in[12];
  const float* ln2g = (const float*)d_in[13];
  const float* ln2b = (const float*)d_in[14];

  float* out  = (float*)d_out;
  float* glog = out + (size_t)TT*DM;

  char* ws = (char*)d_ws;
  float* qkvf    = (float*)(ws + OFF_R0);
  float* attnout = (float*)(ws + OFF_R0);
  u16*   hbuf    = (u16*)  (ws + OFF_R0);
  float* ctxf    = (float*)(ws + OFF_R1);
  u16*   ybuf    = (u16*)  (ws + OFF_R1);
  float* xf      = (float*)(ws + OFF_R2);
  u16*   xg      = (u16*)  (ws + OFF_R3);
  int*   top2e   = (int*)  (ws + OFF_RT);
  float* p0a     = (float*)(ws + OFF_RT + 32768);
  float* p1a     = (float*)(ws + OFF_RT + 65536);
  int*   counts  = (int*)  (ws + OFF_RT + 98304);
  int*   offs    = (int*)  (ws + OFF_RT + 98336);
  int*   cursors = (int*)  (ws + OFF_RT + 98400);
  int*   rowmap  = (int*)  (ws + OFF_RT + 98432);
  int*   tokslot = (int*)  (ws + OFF_RT + 168064);

  hipMemsetAsync(counts, 0, 8*sizeof(int), stream);

  // QKV projection (split-fp16 MFMA): [8192,1024]@[3072,1024]^T
  gemm_f16x2_kernel<0><<<dim3(48,64),256,0,stream>>>(src, inw, inb, nullptr, qkvf, 1024, 3072);
  // flash attention (split-fp16 MFMA)
  attn_mfma_kernel<<<dim3(32,64),256,0,stream>>>(qkvf, ctxf);
  // out projection + residual (split-fp16 MFMA)
  gemm_f16x2_kernel<1><<<dim3(16,64),256,0,stream>>>(ctxf, ow, ob, src, attnout, 1024, 1024);
  // LN1 -> x (f32)
  ln_kernel<<<8192,256,0,stream>>>(attnout, ln1g, ln1b, xf);
  // gate + top2 + counts (fp32)
  gate_kernel<<<2048,256,0,stream>>>(xf, gw, gb, glog, top2e, p0a, p1a, counts);
  // routing bookkeeping
  route_offsets_kernel<<<1,256,0,stream>>>(counts, offs, cursors, rowmap);
  route_assign_kernel<<<32,256,0,stream>>>(top2e, offs, cursors, rowmap, tokslot);
  // gather x rows (bf16) into per-expert segments
  gather_kernel<<<MPAD,256,0,stream>>>(rowmap, xf, xg);
  // expert FFN (bf16 MFMA)
  gemm_moe_kernel<1024,0><<<dim3(32,136),256,0,stream>>>(xg, w1, b1, hbuf, offs, DHID);
  gemm_moe_kernel<4096,1><<<dim3(8,136),256,0,stream>>>(hbuf, w2, b2, ybuf, offs, DM);
  // combine + LN2 -> out
  combine_ln2_kernel<<<8192,256,0,stream>>>(xf, ybuf, tokslot, p0a, p1a, ln2g, ln2b, out);
}

// Round 3
// 1670.867 us; speedup vs baseline: 1.8854x; 1.0900x over previous
//
#include <hip/hip_runtime.h>
#include <cstdint>

#define DEV static __device__ __forceinline__

typedef unsigned short u16;
typedef unsigned int   u32;
typedef __attribute__((ext_vector_type(8))) short bf16x8;
typedef __attribute__((ext_vector_type(8))) _Float16 f16x8;
typedef __attribute__((ext_vector_type(4))) float f32x4;

constexpr int TT   = 8192;
constexpr int DM   = 1024;
constexpr int DHID = 4096;
constexpr int MPAD = 17408;  // 136*128

// ---- ws layout (bytes). Peak usage identical to prior passing rounds (247.7MB).
// late-phase (stable) regions:
constexpr size_t O_HBUF = 0;            // 142,606,336  [moe1->moe2]
constexpr size_t O_XG   = 142606336;    //  35,651,584  [gather->moe1]
constexpr size_t O_YBUF = 178257920;    //  35,651,584  [moe2->combine]
constexpr size_t O_XF   = 213909504;    //  33,554,432  [ln1->combine]
constexpr size_t O_RT   = 247463936;    //     262,144
// early-phase overlays (all dead before their hosts are written):
constexpr size_t O_SRCH = 0;            // src hi/lo planes [prep->qkv]
constexpr size_t O_SRCL = 16777216;
constexpr size_t O_INWH = 33554432;     // in_proj_w planes
constexpr size_t O_INWL = 39845888;
constexpr size_t O_OWH  = 46137344;     // out_proj_w planes [prep->outproj]
constexpr size_t O_OWL  = 48234496;
constexpr size_t O_QH   = 50331648;     // Q planes [qkv->attn]
constexpr size_t O_QL   = 67108864;
constexpr size_t O_KH   = 83886080;     // K planes (pre-swizzled) [qkv->attn]
constexpr size_t O_KL   = 100663296;
constexpr size_t O_VF   = 117440512;    // V f32 [qkv->prep_vt]
constexpr size_t O_VTH  = 150994944;    // V^T planes (pre-swizzled) [prep_vt->attn]
constexpr size_t O_VTL  = 167772160;
constexpr size_t O_CTXH = 184549376;    // ctx planes (pre-swizzled) [attn->outproj]
constexpr size_t O_CTXL = 201326592;
constexpr size_t O_AOUT = 0;            // attnout f32 [outproj->ln1]

DEV u16 f2b(float f){ u32 b = __builtin_bit_cast(u32, f); return (u16)((b + 0x7FFFu + ((b>>16)&1u))>>16); }
DEV float b2f(u16 u){ u32 b = ((u32)u)<<16; return __builtin_bit_cast(float, b); }

DEV void split2(float x, float y, u32& hi, u32& lo){
  _Float16 hx = (_Float16)x, hy = (_Float16)y;
  float rx = (x - (float)hx)*1024.f, ry = (y - (float)hy)*1024.f;
  _Float16 lx = (_Float16)rx, ly = (_Float16)ry;
  hi = (u32)__builtin_bit_cast(u16,hx) | ((u32)__builtin_bit_cast(u16,hy)<<16);
  lo = (u32)__builtin_bit_cast(u16,lx) | ((u32)__builtin_bit_cast(u16,ly)<<16);
}
DEV void split1(float x, u16& h, u16& l){
  _Float16 hx = (_Float16)x;
  float rx = (x - (float)hx)*1024.f;
  h = __builtin_bit_cast(u16, hx);
  l = __builtin_bit_cast(u16, (_Float16)rx);
}

// async global->LDS 16B copy (linear dest: wave base + lane*16)
DEV void gld16(const u16* g, u16* l){
  __builtin_amdgcn_global_load_lds(
    (const __attribute__((address_space(1))) void*)g,
    (__attribute__((address_space(3))) void*)l, 16, 0, 0);
}

// ---------------------------------------------------------------------------
// prep: f32 [R][1024] -> fp16 hi/lo planes, 16B chunks swizzled by (row&7)
// within each 64-col group. One thread = one 16B output chunk.
// ---------------------------------------------------------------------------
__global__ __launch_bounds__(256) void prep_split_kernel(
    const float* __restrict__ src, u16* __restrict__ hi, u16* __restrict__ lo)
{
  const int g = blockIdx.x*256 + threadIdx.x;
  const int r = g >> 7;           // 128 chunks per row
  const int ci = g & 127;
  const float4 v0 = *(const float4*)&src[(size_t)r*1024 + ci*8];
  const float4 v1 = *(const float4*)&src[(size_t)r*1024 + ci*8 + 4];
  u32 h[4], l4[4];
  split2(v0.x,v0.y,h[0],l4[0]); split2(v0.z,v0.w,h[1],l4[1]);
  split2(v1.x,v1.y,h[2],l4[2]); split2(v1.z,v1.w,h[3],l4[3]);
  const int co = (ci & ~7) | ((ci ^ r) & 7);
  *(uint4*)&hi[(size_t)r*1024 + co*8] = make_uint4(h[0],h[1],h[2],h[3]);
  *(uint4*)&lo[(size_t)r*1024 + co*8] = make_uint4(l4[0],l4[1],l4[2],l4[3]);
}

// ---------------------------------------------------------------------------
// prep_vt: V f32 [8192][1024] -> VT hi/lo planes [64bh][64d][2048s],
// s-chunks swizzled by (d&7) within each 64-s group. LDS transpose.
// grid (bh=64, stile=32), block 256.
// ---------------------------------------------------------------------------
__global__ __launch_bounds__(256) void prep_vt_kernel(
    const float* __restrict__ Vf, u16* __restrict__ VTh, u16* __restrict__ VTl)
{
  __shared__ float fsm[64*65];
  const int bh = blockIdx.x, st = blockIdx.y;
  const int bb = bh>>4, h = bh&15, go = h*64;
  const int s0 = bb*2048 + st*64;
  const int t = threadIdx.x;
  {
    const int r = t>>2, c0 = (t&3)*16;
    #pragma unroll
    for (int j=0;j<4;j++){
      const float4 v = *(const float4*)&Vf[(size_t)(s0+r)*1024 + go + c0 + 4*j];
      fsm[r*65 + c0 + 4*j+0]=v.x; fsm[r*65 + c0 + 4*j+1]=v.y;
      fsm[r*65 + c0 + 4*j+2]=v.z; fsm[r*65 + c0 + 4*j+3]=v.w;
    }
  }
  __syncthreads();
  const int d = t>>2, qs = t&3;
  #pragma unroll
  for (int j2=0;j2<2;j2++){
    const int q = qs*2 + j2;
    float v[8];
    #pragma unroll
    for (int jj=0;jj<8;jj++) v[jj] = fsm[(q*8+jj)*65 + d];
    u32 h0,h1,h2,h3,l0,l1,l2,l3;
    split2(v[0],v[1],h0,l0); split2(v[2],v[3],h1,l1);
    split2(v[4],v[5],h2,l2); split2(v[6],v[7],h3,l3);
    const int cst = q ^ (d&7);
    const size_t base = (size_t)(bh*64 + d)*2048 + st*64 + cst*8;
    *(uint4*)&VTh[base] = make_uint4(h0,h1,h2,h3);
    *(uint4*)&VTl[base] = make_uint4(l0,l1,l2,l3);
  }
}

// ---------------------------------------------------------------------------
// split-fp16 MFMA GEMM from hi/lo planes (pre-swizzled), global_load_lds staging.
// C = A[M,K] @ W[N,K]^T + bias. Tile 128x64, BK=64, 4 waves (2x2).
// EPI 0: QKV epilogue (Q planes scaled+split, K planes split+swizzled, V f32)
// EPI 1: out = v + resid (f32)
// ---------------------------------------------------------------------------
template<int EPI>
__global__ __launch_bounds__(256,2) void gemm_pair_kernel(
    const u16* __restrict__ Ahi, const u16* __restrict__ Alo,
    const u16* __restrict__ Bhi, const u16* __restrict__ Blo,
    const float* __restrict__ bias, const float* __restrict__ resid,
    float* __restrict__ outf,
    u16* __restrict__ Qh, u16* __restrict__ Ql,
    u16* __restrict__ Kh, u16* __restrict__ Kl, float* __restrict__ Vf,
    int K, int N)
{
  __shared__ __align__(16) u16 sm[24576];
  u16* As_hi = sm;          // [128][64]
  u16* As_lo = sm + 8192;
  u16* Bs_hi = sm + 16384;  // [64][64]
  u16* Bs_lo = sm + 20480;
  const int m0 = blockIdx.y*128, n0 = blockIdx.x*64;
  const int t = threadIdx.x, l = t&63, w = t>>6;
  const int lr = l&15, lg = l>>4;
  const int wr = (w>>1)*64, wc = (w&1)*32;
  const int srow = w*8 + (l>>3);   // 0..31 within a 32-row staging op
  const int sch  = l&7;
  f32x4 a0[4][2], a1[4][2];
  #pragma unroll
  for (int m=0;m<4;m++)
    #pragma unroll
    for (int n=0;n<2;n++){ a0[m][n]=(f32x4){0,0,0,0}; a1[m][n]=(f32x4){0,0,0,0}; }
  for (int k0=0; k0<K; k0+=64){
    __syncthreads();
    #pragma unroll
    for (int op=0; op<4; ++op){
      const int r = op*32 + srow;
      const size_t src = (size_t)(m0+r)*K + k0 + sch*8;  // planes pre-swizzled: straight copy
      gld16(&Ahi[src], &As_hi[(op*32 + w*8)*64]);
      gld16(&Alo[src], &As_lo[(op*32 + w*8)*64]);
    }
    #pragma unroll
    for (int op=0; op<2; ++op){
      const int r = op*32 + srow;
      const size_t src = (size_t)(n0+r)*K + k0 + sch*8;
      gld16(&Bhi[src], &Bs_hi[(op*32 + w*8)*64]);
      gld16(&Blo[src], &Bs_lo[(op*32 + w*8)*64]);
    }
    __syncthreads();
    #pragma unroll
    for (int s=0;s<2;s++){
      f16x8 bh[2], bl[2];
      #pragma unroll
      for (int n=0;n<2;n++){
        const int bi = (wc+16*n+lr)*64 + (((4*s+lg) ^ (lr&7))<<3);
        bh[n] = *(const f16x8*)&Bs_hi[bi];
        bl[n] = *(const f16x8*)&Bs_lo[bi];
      }
      #pragma unroll
      for (int m=0;m<4;m++){
        const int ai = (wr+16*m+lr)*64 + (((4*s+lg) ^ (lr&7))<<3);
        const f16x8 ah = *(const f16x8*)&As_hi[ai];
        const f16x8 al = *(const f16x8*)&As_lo[ai];
        #pragma unroll
        for (int n=0;n<2;n++){
          a0[m][n] = __builtin_amdgcn_mfma_f32_16x16x32_f16(ah, bh[n], a0[m][n], 0,0,0);
          a1[m][n] = __builtin_amdgcn_mfma_f32_16x16x32_f16(ah, bl[n], a1[m][n], 0,0,0);
          a1[m][n] = __builtin_amdgcn_mfma_f32_16x16x32_f16(al, bh[n], a1[m][n], 0,0,0);
        }
      }
    }
  }
  #pragma unroll
  for (int n2=0;n2<2;n2++){
    const int gn = n0 + wc + 16*n2 + lr;
    const float be = bias[gn];
    #pragma unroll
    for (int m=0;m<4;m++){
      #pragma unroll
      for (int r=0;r<4;r++){
        const int gm = m0 + wr + 16*m + 4*lg + r;
        float v = a0[m][n2][r] + a1[m][n2][r]*9.765625e-4f + be;
        if (EPI==0){
          if (gn < 1024){
            u16 hh,ll; split1(v*0.125f, hh, ll);
            Qh[(size_t)gm*1024 + gn] = hh; Ql[(size_t)gm*1024 + gn] = ll;
          } else if (gn < 2048){
            const int c = gn - 1024;
            const int cst = (c & ~63) | ((((c>>3) ^ gm) & 7)<<3) | (c & 7);
            u16 hh,ll; split1(v, hh, ll);
            Kh[(size_t)gm*1024 + cst] = hh; Kl[(size_t)gm*1024 + cst] = ll;
          } else {
            Vf[(size_t)gm*1024 + (gn-2048)] = v;
          }
        } else {
          outf[(size_t)gm*N + gn] = v + resid[(size_t)gm*N + gn];
        }
      }
    }
  }
}

// ---------------------------------------------------------------------------
// split-fp16 MFMA flash attention v3. grid (32 qtiles, 64 b*h), 4 waves.
// Q frags direct global->reg; K/V staged via global_load_lds from planes.
// ---------------------------------------------------------------------------
__global__ __launch_bounds__(256,2) void attn_mfma_kernel(
    const u16* __restrict__ Qhp, const u16* __restrict__ Qlp,
    const u16* __restrict__ Khp, const u16* __restrict__ Klp,
    const u16* __restrict__ VTh, const u16* __restrict__ VTl,
    u16* __restrict__ ctxh, u16* __restrict__ ctxl)
{
  __shared__ __align__(16) u16 sm[24576];
  u16* Khs = sm;          // [64 key][64 d]
  u16* Kls = sm + 4096;
  u16* Vhs = sm + 8192;   // [64 d][64 key]
  u16* Vls = sm + 12288;
  u16* Phs = sm + 16384;  // [64 q][64 key]
  u16* Pls = sm + 20480;
  float* fsm = (float*)sm;
  const int bh = blockIdx.y, bb = bh>>4, h = bh&15;
  const int tb = bb*2048, q0 = blockIdx.x*64, go = h*64;
  const int t = threadIdx.x, l = t&63, w = t>>6;
  const int lr = l&15, lg = l>>4;
  const int srow = w*8 + (l>>3);
  const int sch  = l&7;

  // Q fragments straight from global (unswizzled plane)
  f16x8 qh[2], ql[2];
  {
    const size_t qr = (size_t)(tb + q0 + 16*w + lr)*1024 + go;
    #pragma unroll
    for (int s=0;s<2;s++){
      qh[s] = *(const f16x8*)&Qhp[qr + 32*s + 8*lg];
      ql[s] = *(const f16x8*)&Qlp[qr + 32*s + 8*lg];
    }
  }

  float m_ = -1e30f, l_ = 0.f;
  f32x4 c0a[4], c1a[4];
  #pragma unroll
  for (int m=0;m<4;m++){ c0a[m]=(f32x4){0,0,0,0}; c1a[m]=(f32x4){0,0,0,0}; }

  for (int kt=0; kt<32; ++kt){
    const int kb = tb + kt*64;
    __syncthreads();
    #pragma unroll
    for (int op=0; op<2; ++op){
      const int r = op*32 + srow;                       // key-row / d-row
      const size_t ksrc = (size_t)(kb + r)*1024 + go + sch*8;
      const size_t vsrc = (size_t)(bh*64 + r)*2048 + kt*64 + sch*8;
      gld16(&Khp[ksrc], &Khs[(op*32 + w*8)*64]);
      gld16(&Klp[ksrc], &Kls[(op*32 + w*8)*64]);
      gld16(&VTh[vsrc], &Vhs[(op*32 + w*8)*64]);
      gld16(&VTl[vsrc], &Vls[(op*32 + w*8)*64]);
    }
    __syncthreads();
    // S^T = K·Q^T
    f32x4 s0[4], s1[4];
    #pragma unroll
    for (int m=0;m<4;m++){ s0[m]=(f32x4){0,0,0,0}; s1[m]=(f32x4){0,0,0,0}; }
    #pragma unroll
    for (int s=0;s<2;s++){
      #pragma unroll
      for (int m=0;m<4;m++){
        const int ai = (16*m+lr)*64 + (((4*s+lg) ^ (lr&7))<<3);
        const f16x8 ah = *(const f16x8*)&Khs[ai];
        const f16x8 al = *(const f16x8*)&Kls[ai];
        s0[m] = __builtin_amdgcn_mfma_f32_16x16x32_f16(ah, qh[s], s0[m], 0,0,0);
        s1[m] = __builtin_amdgcn_mfma_f32_16x16x32_f16(ah, ql[s], s1[m], 0,0,0);
        s1[m] = __builtin_amdgcn_mfma_f32_16x16x32_f16(al, qh[s], s1[m], 0,0,0);
      }
    }
    // online softmax (lane q = 16w+lr across lanes l, l^16, l^32, l^48)
    float p[4][4];
    float mx = -1e30f;
    #pragma unroll
    for (int m=0;m<4;m++)
      #pragma unroll
      for (int r=0;r<4;r++){
        const float v = s0[m][r] + s1[m][r]*9.765625e-4f;
        p[m][r] = v; mx = fmaxf(mx, v);
      }
    mx = fmaxf(mx, __shfl_xor(mx,16));
    mx = fmaxf(mx, __shfl_xor(mx,32));
    const float mn = fmaxf(m_, mx);
    const float sc = __expf(m_ - mn);
    float rs = 0.f;
    #pragma unroll
    for (int m=0;m<4;m++)
      #pragma unroll
      for (int r=0;r<4;r++){ const float e = __expf(p[m][r]-mn); p[m][r]=e; rs += e; }
    rs += __shfl_xor(rs,16);
    rs += __shfl_xor(rs,32);
    l_ = l_*sc + rs; m_ = mn;
    #pragma unroll
    for (int m=0;m<4;m++){ c0a[m] *= sc; c1a[m] *= sc; }
    // P [q][key] hi/lo
    const int prow = 16*w + lr;
    #pragma unroll
    for (int m=0;m<4;m++){
      u32 h0,l0,h1,l1;
      split2(p[m][0], p[m][1], h0, l0);
      split2(p[m][2], p[m][3], h1, l1);
      const int pi = prow*64 + ((16*m + 4*lg) ^ ((lr&7)<<3));
      *(uint2*)&Phs[pi] = make_uint2(h0,h1);
      *(uint2*)&Pls[pi] = make_uint2(l0,l1);
    }
    // PV: ctx^T[d][q] += V^T · P^T
    #pragma unroll
    for (int s=0;s<2;s++){
      const int bi = prow*64 + ((32*s + 8*lg) ^ ((lr&7)<<3));
      const f16x8 ph = *(const f16x8*)&Phs[bi];
      const f16x8 pl = *(const f16x8*)&Pls[bi];
      #pragma unroll
      for (int m=0;m<4;m++){
        const int ai = (16*m+lr)*64 + (((4*s+lg) ^ (lr&7))<<3);
        const f16x8 vh8 = *(const f16x8*)&Vhs[ai];
        const f16x8 vl8 = *(const f16x8*)&Vls[ai];
        c0a[m] = __builtin_amdgcn_mfma_f32_16x16x32_f16(vh8, ph, c0a[m], 0,0,0);
        c1a[m] = __builtin_amdgcn_mfma_f32_16x16x32_f16(vh8, pl, c1a[m], 0,0,0);
        c1a[m] = __builtin_amdgcn_mfma_f32_16x16x32_f16(vl8, ph, c1a[m], 0,0,0);
      }
    }
  }
  // epilogue: normalize, transpose via LDS f32 [64][68], split -> ctx planes
  __syncthreads();
  {
    const float inv = 1.f/l_;
    const int q = 16*w + lr;
    #pragma unroll
    for (int m=0;m<4;m++)
      #pragma unroll
      for (int r=0;r<4;r++)
        fsm[q*68 + 16*m + 4*lg + r] = (c0a[m][r] + c1a[m][r]*9.765625e-4f)*inv;
  }
  __syncthreads();
  {
    const int sr2 = t>>2, qs2 = t&3;
    const int row = tb + q0 + sr2;
    #pragma unroll
    for (int j2=0;j2<2;j2++){
      const int cch = qs2*2 + j2;
      float v[8];
      #pragma unroll
      for (int jj=0;jj<8;jj++) v[jj] = fsm[sr2*68 + cch*8 + jj];
      u32 h0,h1,h2,h3,l0,l1,l2,l3;
      split2(v[0],v[1],h0,l0); split2(v[2],v[3],h1,l1);
      split2(v[4],v[5],h2,l2); split2(v[6],v[7],h3,l3);
      const int cst = cch ^ (row&7);
      const size_t base = (size_t)row*1024 + go + cst*8;
      *(uint4*)&ctxh[base] = make_uint4(h0,h1,h2,h3);
      *(uint4*)&ctxl[base] = make_uint4(l0,l1,l2,l3);
    }
  }
}

// ---------------------------------------------------------------------------
// LayerNorm (f32 -> f32)
// ---------------------------------------------------------------------------
__global__ __launch_bounds__(256) void ln_kernel(const float* __restrict__ in,
    const float* __restrict__ g, const float* __restrict__ b, float* __restrict__ o)
{
  const int r = blockIdx.x, t = threadIdx.x;
  const float4 v = *(const float4*)&in[(size_t)r*1024 + t*4];
  float s = v.x+v.y+v.z+v.w;
  float q = v.x*v.x + v.y*v.y + v.z*v.z + v.w*v.w;
  #pragma unroll
  for (int off=1; off<64; off<<=1){ s += __shfl_xor(s,off); q += __shfl_xor(q,off); }
  __shared__ float red[8];
  const int w = t>>6, lane = t&63;
  if (lane==0){ red[w]=s; red[4+w]=q; }
  __syncthreads();
  s = red[0]+red[1]+red[2]+red[3];
  q = red[4]+red[5]+red[6]+red[7];
  const float mu = s*(1.f/1024.f);
  const float var = q*(1.f/1024.f) - mu*mu;
  const float rstd = rsqrtf(var + 1e-5f);
  const float4 gv = *(const float4*)&g[t*4];
  const float4 bv = *(const float4*)&b[t*4];
  *(float4*)&o[(size_t)r*1024 + t*4] = make_float4(
    (v.x-mu)*rstd*gv.x + bv.x, (v.y-mu)*rstd*gv.y + bv.y,
    (v.z-mu)*rstd*gv.z + bv.z, (v.w-mu)*rstd*gv.w + bv.w);
}

// ---------------------------------------------------------------------------
// gate / routing / gather  (unchanged)
// ---------------------------------------------------------------------------
__global__ __launch_bounds__(256) void gate_kernel(
    const float* __restrict__ xf, const float* __restrict__ gw, const float* __restrict__ gb,
    float* __restrict__ glog, int* __restrict__ top2e,
    float* __restrict__ p0a, float* __restrict__ p1a, int* __restrict__ counts)
{
  const int tok  = blockIdx.x*4 + (threadIdx.x>>6);
  const int lane = threadIdx.x & 63;
  float part[8] = {};
  const float* xr = xf + (size_t)tok*1024;
  #pragma unroll
  for (int kk=0; kk<16; kk++){
    const int d = kk*64 + lane;
    const float xv = xr[d];
    #pragma unroll
    for (int e=0;e<8;e++) part[e] = fmaf(xv, gw[e*1024+d], part[e]);
  }
  #pragma unroll
  for (int e=0;e<8;e++){
    float s = part[e];
    s += __shfl_xor(s,1); s += __shfl_xor(s,2); s += __shfl_xor(s,4);
    s += __shfl_xor(s,8); s += __shfl_xor(s,16); s += __shfl_xor(s,32);
    part[e] = s + gb[e];
  }
  if (lane==0){
    #pragma unroll
    for (int e=0;e<8;e++) glog[(size_t)tok*8+e] = part[e];
    float v0=-1e30f; int e0=0;
    #pragma unroll
    for (int e=0;e<8;e++) if (part[e] > v0){ v0=part[e]; e0=e; }
    float v1=-1e30f; int e1=0;
    #pragma unroll
    for (int e=0;e<8;e++) if (e!=e0 && part[e] > v1){ v1=part[e]; e1=e; }
    const float p0 = 1.f/(1.f + __expf(v1-v0));
    top2e[tok] = e0 | (e1<<4);
    p0a[tok] = p0; p1a[tok] = 1.f - p0;
    atomicAdd(&counts[e0],1); atomicAdd(&counts[e1],1);
  }
}

__global__ void route_offsets_kernel(const int* __restrict__ counts, int* __restrict__ offs,
                                     int* __restrict__ cursors, int* __restrict__ rowmap)
{
  const int t = threadIdx.x;
  if (t==0){
    int a=0;
    for (int e=0;e<8;e++){ offs[e]=a; a += (counts[e]+127)&~127; }
    offs[8]=a;
  }
  if (t<8) cursors[t]=0;
  for (int i=t;i<MPAD;i+=256) rowmap[i] = -1;
}

__global__ void route_assign_kernel(const int* __restrict__ top2e, const int* __restrict__ offs,
    int* __restrict__ cursors, int* __restrict__ rowmap, int* __restrict__ tokslot)
{
  const int tok = blockIdx.x*256 + threadIdx.x;
  const int pk = top2e[tok];
  const int e0 = pk & 15, e1 = pk >> 4;
  const int s0 = offs[e0] + atomicAdd(&cursors[e0], 1);
  const int s1 = offs[e1] + atomicAdd(&cursors[e1], 1);
  rowmap[s0] = tok; rowmap[s1] = tok;
  tokslot[2*tok] = s0; tokslot[2*tok+1] = s1;
}

__global__ __launch_bounds__(256) void gather_kernel(const int* __restrict__ rowmap,
    const float* __restrict__ xf, u16* __restrict__ xg)
{
  const int slot = blockIdx.x, t = threadIdx.x;
  u16* dst = xg + (size_t)slot*1024;
  const int r = rowmap[slot];
  if (r >= 0){
    const float4 v = *(const float4*)&xf[(size_t)r*1024 + t*4];
    uint2 p; p.x = (u32)f2b(v.x) | ((u32)f2b(v.y)<<16);
             p.y = (u32)f2b(v.z) | ((u32)f2b(v.w)<<16);
    *(uint2*)&dst[t*4] = p;
  } else {
    uint2 z; z.x=0u; z.y=0u;
    *(uint2*)&dst[t*4] = z;
  }
}

// ---------------------------------------------------------------------------
// MoE expert GEMM (unchanged): bf16 MFMA, 128x128, BK=32.
// ---------------------------------------------------------------------------
template<int KDIM, int EPI>
__global__ __launch_bounds__(256,2) void gemm_moe_kernel(
    const u16* __restrict__ A, const float* __restrict__ Wbase,
    const float* __restrict__ biasbase, u16* __restrict__ C,
    const int* __restrict__ offs, int N)
{
  constexpr int LS = 56;
  __shared__ u16 As[128*LS];
  __shared__ u16 Bs[128*LS];
  const int m0 = blockIdx.y*128, n0 = blockIdx.x*128;
  int e = 0;
  #pragma unroll
  for (int i=1;i<8;i++) if (offs[i] <= m0) e = i;
  const float* W    = Wbase + (size_t)e*N*KDIM;
  const float* bias = biasbase + (size_t)e*N;
  const int t = threadIdx.x;
  const int w = t>>6, lane = t&63;
  const int wr = (w>>1)*64, wc = (w&1)*64;
  const int lr = lane&15, lk = (lane>>4)*8;
  const int ar = t>>2, ac8 = (t&3)*8;
  const int br = t>>3, bc4 = (t&7)*4;
  f32x4 acc[4][4];
  #pragma unroll
  for (int mi=0;mi<4;mi++)
    #pragma unroll
    for (int ni=0;ni<4;ni++){ acc[mi][ni][0]=0.f; acc[mi][ni][1]=0.f; acc[mi][ni][2]=0.f; acc[mi][ni][3]=0.f; }
  for (int k0=0; k0<KDIM; k0+=32){
    __syncthreads();
    #pragma unroll
    for (int it=0; it<2; it++){
      const int r = ar + it*64;
      *(uint4*)&As[r*LS + ac8] = *(const uint4*)&A[(size_t)(m0+r)*KDIM + k0 + ac8];
    }
    #pragma unroll
    for (int it=0; it<4; it++){
      const int r = br + it*32;
      const float4 v = *(const float4*)&W[(size_t)(n0+r)*KDIM + k0 + bc4];
      uint2 p; p.x = (u32)f2b(v.x) | ((u32)f2b(v.y)<<16);
               p.y = (u32)f2b(v.z) | ((u32)f2b(v.w)<<16);
      *(uint2*)&Bs[r*LS + bc4] = p;
    }
    __syncthreads();
    bf16x8 af[4], bfr[4];
    #pragma unroll
    for (int mi=0;mi<4;mi++) af[mi]  = *(const bf16x8*)&As[(wr+mi*16+lr)*LS + lk];
    #pragma unroll
    for (int ni=0;ni<4;ni++) bfr[ni] = *(const bf16x8*)&Bs[(wc+ni*16+lr)*LS + lk];
    #pragma unroll
    for (int mi=0;mi<4;mi++)
      #pragma unroll
      for (int ni=0;ni<4;ni++)
        acc[mi][ni] = __builtin_amdgcn_mfma_f32_16x16x32_bf16(af[mi], bfr[ni], acc[mi][ni], 0,0,0);
  }
  const int lr4 = (lane>>4)*4, lc = lane&15;
  #pragma unroll
  for (int mi=0;mi<4;mi++)
    #pragma unroll
    for (int ni=0;ni<4;ni++){
      const int gn = n0 + wc + ni*16 + lc;
      const float be = bias[gn];
      #pragma unroll
      for (int j=0;j<4;j++){
        const int gm = m0 + wr + mi*16 + lr4 + j;
        float v = acc[mi][ni][j] + be;
        if (EPI==0) v = fmaxf(v, 0.f);
        C[(size_t)gm*N + gn] = f2b(v);
      }
    }
}

// ---------------------------------------------------------------------------
// combine + LN2
// ---------------------------------------------------------------------------
__global__ __launch_bounds__(256) void combine_ln2_kernel(
    const float* __restrict__ xf, const u16* __restrict__ y, const int* __restrict__ tokslot,
    const float* __restrict__ p0a, const float* __restrict__ p1a,
    const float* __restrict__ g, const float* __restrict__ b, float* __restrict__ o)
{
  const int tok = blockIdx.x, t = threadIdx.x;
  const int s0 = tokslot[2*tok], s1 = tokslot[2*tok+1];
  const float w0 = p0a[tok], w1 = p1a[tok];
  const float4 xv = *(const float4*)&xf[(size_t)tok*1024 + t*4];
  const uint2 ya = *(const uint2*)&y[(size_t)s0*1024 + t*4];
  const uint2 yb = *(const uint2*)&y[(size_t)s1*1024 + t*4];
  const float va[4] = {b2f((u16)(ya.x&0xFFFF)), b2f((u16)(ya.x>>16)),
                       b2f((u16)(ya.y&0xFFFF)), b2f((u16)(ya.y>>16))};
  const float vb[4] = {b2f((u16)(yb.x&0xFFFF)), b2f((u16)(yb.x>>16)),
                       b2f((u16)(yb.y&0xFFFF)), b2f((u16)(yb.y>>16))};
  const float xe[4] = {xv.x, xv.y, xv.z, xv.w};
  float vv[4];
  #pragma unroll
  for (int i=0;i<4;i++) vv[i] = xe[i] + w0*va[i] + w1*vb[i];
  float s = vv[0]+vv[1]+vv[2]+vv[3];
  float q = vv[0]*vv[0]+vv[1]*vv[1]+vv[2]*vv[2]+vv[3]*vv[3];
  #pragma unroll
  for (int off=1; off<64; off<<=1){ s += __shfl_xor(s,off); q += __shfl_xor(q,off); }
  __shared__ float red[8];
  const int w = t>>6, lane = t&63;
  if (lane==0){ red[w]=s; red[4+w]=q; }
  __syncthreads();
  s = red[0]+red[1]+red[2]+red[3];
  q = red[4]+red[5]+red[6]+red[7];
  const float mu = s*(1.f/1024.f);
  const float var = q*(1.f/1024.f) - mu*mu;
  const float rstd = rsqrtf(var + 1e-5f);
  const float4 gv = *(const float4*)&g[t*4];
  const float4 bv = *(const float4*)&b[t*4];
  *(float4*)&o[(size_t)tok*1024 + t*4] = make_float4(
    (vv[0]-mu)*rstd*gv.x + bv.x, (vv[1]-mu)*rstd*gv.y + bv.y,
    (vv[2]-mu)*rstd*gv.z + bv.z, (vv[3]-mu)*rstd*gv.w + bv.w);
}

// ---------------------------------------------------------------------------
extern "C" void kernel_launch(void* const* d_in, const int* in_sizes, int n_in,
                              void* d_out, int out_size, void* d_ws, size_t ws_size,
                              hipStream_t stream)
{
  const float* src  = (const float*)d_in[0];
  const float* inw  = (const float*)d_in[1];
  const float* inb  = (const float*)d_in[2];
  const float* ow   = (const float*)d_in[3];
  const float* ob   = (const float*)d_in[4];
  const float* ln1g = (const float*)d_in[5];
  const float* ln1b = (const float*)d_in[6];
  const float* gw   = (const float*)d_in[7];
  const float* gb   = (const float*)d_in[8];
  const float* w1   = (const float*)d_in[9];
  const float* b1   = (const float*)d_in[10];
  const float* w2   = (const float*)d_in[11];
  const float* b2   = (const float*)d_in[12];
  const float* ln2g = (const float*)d_in[13];
  const float* ln2b = (const float*)d_in[14];

  float* out  = (float*)d_out;
  float* glog = out + (size_t)TT*DM;

  char* ws = (char*)d_ws;
  u16*   hbuf    = (u16*)  (ws + O_HBUF);
  u16*   xg      = (u16*)  (ws + O_XG);
  u16*   ybuf    = (u16*)  (ws + O_YBUF);
  float* xf      = (float*)(ws + O_XF);
  u16*   srch    = (u16*)  (ws + O_SRCH);
  u16*   srcl    = (u16*)  (ws + O_SRCL);
  u16*   inwh    = (u16*)  (ws + O_INWH);
  u16*   inwl    = (u16*)  (ws + O_INWL);
  u16*   owh     = (u16*)  (ws + O_OWH);
  u16*   owl     = (u16*)  (ws + O_OWL);
  u16*   Qh      = (u16*)  (ws + O_QH);
  u16*   Ql      = (u16*)  (ws + O_QL);
  u16*   Kh      = (u16*)  (ws + O_KH);
  u16*   Kl      = (u16*)  (ws + O_KL);
  float* Vf      = (float*)(ws + O_VF);
  u16*   VTh     = (u16*)  (ws + O_VTH);
  u16*   VTl     = (u16*)  (ws + O_VTL);
  u16*   ctxh    = (u16*)  (ws + O_CTXH);
  u16*   ctxl    = (u16*)  (ws + O_CTXL);
  float* attnout = (float*)(ws + O_AOUT);
  int*   top2e   = (int*)  (ws + O_RT);
  float* p0a     = (float*)(ws + O_RT + 32768);
  float* p1a     = (float*)(ws + O_RT + 65536);
  int*   counts  = (int*)  (ws + O_RT + 98304);
  int*   offs    = (int*)  (ws + O_RT + 98336);
  int*   cursors = (int*)  (ws + O_RT + 98400);
  int*   rowmap  = (int*)  (ws + O_RT + 98432);
  int*   tokslot = (int*)  (ws + O_RT + 168064);

  hipMemsetAsync(counts, 0, 8*sizeof(int), stream);

  // P1: split inputs into fp16 hi/lo planes (pre-swizzled)
  prep_split_kernel<<<4096,256,0,stream>>>(src, srch, srcl);
  prep_split_kernel<<<1536,256,0,stream>>>(inw, inwh, inwl);
  prep_split_kernel<<< 512,256,0,stream>>>(ow,  owh,  owl);
  // P2: QKV projection -> Q/K planes + V f32
  gemm_pair_kernel<0><<<dim3(48,64),256,0,stream>>>(srch, srcl, inwh, inwl, inb,
      nullptr, nullptr, Qh, Ql, Kh, Kl, Vf, 1024, 3072);
  // P3: V transpose -> VT planes
  prep_vt_kernel<<<dim3(64,32),256,0,stream>>>(Vf, VTh, VTl);
  // P4: flash attention -> ctx planes
  attn_mfma_kernel<<<dim3(32,64),256,0,stream>>>(Qh, Ql, Kh, Kl, VTh, VTl, ctxh, ctxl);
  // P5: out projection + residual -> attnout f32
  gemm_pair_kernel<1><<<dim3(16,64),256,0,stream>>>(ctxh, ctxl, owh, owl, ob,
      src, attnout, nullptr, nullptr, nullptr, nullptr, nullptr, 1024, 1024);
  // P6: LN1 -> xf
  ln_kernel<<<8192,256,0,stream>>>(attnout, ln1g, ln1b, xf);
  // P6.5: gate + routing
  gate_kernel<<<2048,256,0,stream>>>(xf, gw, gb, glog, top2e, p0a, p1a, counts);
  route_offsets_kernel<<<1,256,0,stream>>>(counts, offs, cursors, rowmap);
  route_assign_kernel<<<32,256,0,stream>>>(top2e, offs, cursors, rowmap, tokslot);
  // P7: gather
  gather_kernel<<<MPAD,256,0,stream>>>(rowmap, xf, xg);
  // P8/P9: expert FFN
  gemm_moe_kernel<1024,0><<<dim3(32,136),256,0,stream>>>(xg, w1, b1, hbuf, offs, DHID);
  gemm_moe_kernel<4096,1><<<dim3(8,136),256,0,stream>>>(hbuf, w2, b2, ybuf, offs, DM);
  // P10: combine + LN2
  combine_ln2_kernel<<<8192,256,0,stream>>>(xf, ybuf, tokslot, p0a, p1a, ln2g, ln2b, out);
}